// Round 1
// 730.527 us; speedup vs baseline: 1.0365x; 1.0365x over previous
//
#include <hip/hip_runtime.h>
#include <hip/hip_bf16.h>
#include <cstdint>

#define AS1 __attribute__((address_space(1)))
#define AS3 __attribute__((address_space(3)))

typedef __attribute__((ext_vector_type(8))) __bf16 bf16x8;
typedef __attribute__((ext_vector_type(4))) float f32x4;

__device__ inline unsigned short f2bf(float f) {
    unsigned u = __float_as_uint(f);
    u += 0x7fffu + ((u >> 16) & 1);           // round-to-nearest-even
    return (unsigned short)(u >> 16);
}
__device__ inline float bf_lo(unsigned u) { return __uint_as_float(u << 16); }
__device__ inline float bf_hi(unsigned u) { return __uint_as_float(u & 0xffff0000u); }

// ---------------- fused fp32 -> bf16 cast over all 6 inputs ----------------
struct CastArgs {
    const float* s[6];
    unsigned short* d[6];
    long end[6];        // exclusive prefix ends (elements), multiples of 8
};

__global__ void cast_all(CastArgs a, long total) {
    long e = ((long)blockIdx.x * blockDim.x + threadIdx.x) * 8;
    if (e >= total) return;
    int seg = 0;
#pragma unroll
    for (int i = 0; i < 5; i++) seg += (e >= a.end[seg]) ? 1 : 0;
    long base = seg ? a.end[seg - 1] : 0;
    long local = e - base;
    const float* src = a.s[seg] + local;
    float4 x = *(const float4*)src;
    float4 y = *(const float4*)(src + 4);
    ushort4 lo, hi;
    lo.x = f2bf(x.x); lo.y = f2bf(x.y); lo.z = f2bf(x.z); lo.w = f2bf(x.w);
    hi.x = f2bf(y.x); hi.y = f2bf(y.y); hi.z = f2bf(y.z); hi.w = f2bf(y.w);
    unsigned short* dst = a.d[seg] + local;
    *(ushort4*)dst = lo;
    *(ushort4*)(dst + 4) = hi;
}

// ---------------- bf16 GEMM (128x128 tile), C[m,n] = scale * sum_k A[m,k]*B[n,k] ----
// Proven kernel, now with XCD-aware block swizzle (T1). Used for Q and O GEMMs.
template <int OUTF>
__global__ __launch_bounds__(256, 2)
void gemm_bt(const unsigned short* __restrict__ A, const unsigned short* __restrict__ B,
             void* __restrict__ Cv, int M, int N, int K, float scale) {
    __shared__ __align__(16) unsigned short As[128 * 32];
    __shared__ __align__(16) unsigned short Bs[128 * 32];

    const int t = threadIdx.x;
    const int w = t >> 6, lane = t & 63;
    // XCD swizzle: consecutive work-ids land on the same XCD's L2
    const int nbx = gridDim.x;
    int id = blockIdx.y * nbx + blockIdx.x;
    const int nwg = nbx * gridDim.y;
    if ((nwg & 7) == 0) { const int cpx = nwg >> 3; id = (id & 7) * cpx + (id >> 3); }
    const int bx = id % nbx, by = id / nbx;     // n-tile, m-tile
    const int wr = w >> 1, wc = w & 1;
    const int quad = lane >> 4, lr = lane & 15;

    f32x4 acc[4][4] = {};

    const int srow = t >> 2;
    const int schunk = (t & 3) ^ ((srow >> 1) & 3);
    const unsigned short* gA = A + (size_t)(by * 128 + srow) * K + schunk * 8;
    const unsigned short* gB = B + (size_t)(bx * 128 + srow) * K + schunk * 8;
    char* aBase = (char*)As + w * 1024;             // wave-uniform LDS dst
    char* bBase = (char*)Bs + w * 1024;

    const int rsw = (lr >> 1) & 3;
    const int aoff = quad ^ rsw;                    // LDS chunk to read

    for (int k0 = 0; k0 < K; k0 += 32) {
        __builtin_amdgcn_global_load_lds((const AS1 void*)gA,
                                         (AS3 void*)aBase, 16, 0, 0);
        __builtin_amdgcn_global_load_lds((const AS1 void*)(gA + (size_t)64 * K),
                                         (AS3 void*)(aBase + 4096), 16, 0, 0);
        __builtin_amdgcn_global_load_lds((const AS1 void*)gB,
                                         (AS3 void*)bBase, 16, 0, 0);
        __builtin_amdgcn_global_load_lds((const AS1 void*)(gB + (size_t)64 * K),
                                         (AS3 void*)(bBase + 4096), 16, 0, 0);
        gA += 32; gB += 32;
        __syncthreads();

        bf16x8 af[4], bfr[4];
#pragma unroll
        for (int i = 0; i < 4; i++)
            af[i] = *(const bf16x8*)(As + (wr * 64 + i * 16 + lr) * 32 + aoff * 8);
#pragma unroll
        for (int j = 0; j < 4; j++)
            bfr[j] = *(const bf16x8*)(Bs + (wc * 64 + j * 16 + lr) * 32 + aoff * 8);
#pragma unroll
        for (int i = 0; i < 4; i++)
#pragma unroll
            for (int j = 0; j < 4; j++)
                acc[i][j] = __builtin_amdgcn_mfma_f32_16x16x32_bf16(
                    af[i], bfr[j], acc[i][j], 0, 0, 0);
        __syncthreads();
    }

#pragma unroll
    for (int i = 0; i < 4; i++) {
        int row0 = by * 128 + wr * 64 + i * 16 + quad * 4;
#pragma unroll
        for (int j = 0; j < 4; j++) {
            int col = bx * 128 + wc * 64 + j * 16 + lr;
#pragma unroll
            for (int r = 0; r < 4; r++) {
                float vv = acc[i][j][r] * scale;
                size_t idx = (size_t)(row0 + r) * N + col;
                if (OUTF) ((float*)Cv)[idx] = vv;
                else      ((unsigned short*)Cv)[idx] = f2bf(vv);
            }
        }
    }
}

// ---------------- 256x256 / BK=64 / 8-wave 8-phase bf16 GEMM (KV projection) ----
// C[m,n] = scale * sum_k A[m,k]*B[n,k], bf16 out.  Requires M%256==0, N%256==0,
// K%64==0, K/64 >= 2, grid (N/256, M/256) with nwg%8==0, 512 threads.
//
// LDS: double-buffered A/B tiles, 128 KiB total.  Swizzle: 16B-chunk c of row r
// lives at LDS chunk c ^ (r&7) (staging pre-swizzles the GLOBAL source since
// global_load_lds writes lane-linear).  Every 8-lane phase group of a
// ds_read_b128 then covers all 32 banks exactly once -> conflict-free.
//
// Schedule per K-tile t (buf = t&1), phases 0..3, 16 MFMA each:
//   ph0: read A-quad0 + all B-frags; stage (t+1).A1 -> buf^1
//   ph1: read A-quad1;               stage (t+2).B0 -> buf   (B dead after ph0)
//   ph2: read A-quad2;               stage (t+2).B1 -> buf
//   ph3: read A-quad3;               stage (t+2).A0 -> buf; vmcnt(6)
// vmcnt(6) leaves (t+2)'s 3 half-tiles (6 loads) in flight across the barrier;
// everything through (t+1).A1 has landed -> tile t+1 ready.  Never vmcnt(0)
// in steady state (T4).  s_setprio(1) around each MFMA cluster (T5).
__global__ __launch_bounds__(512, 2)
void gemm256_bt(const unsigned short* __restrict__ A, const unsigned short* __restrict__ B,
                unsigned short* __restrict__ C, int M, int N, int K, float scale) {
    __shared__ __align__(16) unsigned short As[2][256][64];   // 64 KiB
    __shared__ __align__(16) unsigned short Bs[2][256][64];   // 64 KiB
    (void)M;

    const int tid = threadIdx.x;
    const int w = tid >> 6, lane = tid & 63;
    const int quad = lane >> 4, lr = lane & 15;
    const int wr = w >> 2, wc = w & 3;           // 2 (M) x 4 (N) wave grid

    // XCD swizzle (T1): nwg % 8 == 0 guaranteed by launch config
    const int nbx = gridDim.x;
    int id = blockIdx.y * nbx + blockIdx.x;
    const int cpx = (nbx * gridDim.y) >> 3;
    id = (id & 7) * cpx + (id >> 3);
    const int bx = id % nbx, by = id / nbx;

    const int NT = K >> 6;

    // per-lane swizzled chunk byte-offsets (in elements) for fragment reads:
    // chunk = (ks*4 + quad) ^ (row&7), and row&7 == lr&7 for all frag rows
    const int o0 = ((quad ^ (lr & 7))) * 8;
    const int o1 = (((4 | quad) ^ (lr & 7))) * 8;

    // staging: thread tid covers LDS (row = tid>>3, chunk = tid&7) of each
    // 64-row instruction; fetch global chunk (tid&7) ^ (row&7)
    const int sr8 = tid >> 3;                     // 0..63
    const int sch = (tid & 7) ^ (sr8 & 7);
    const unsigned short* gA = A + (size_t)(by * 256 + sr8) * K + sch * 8;
    const unsigned short* gB = B + (size_t)(bx * 256 + sr8) * K + sch * 8;
    char* lA = (char*)&As[0][0][0] + w * 1024;    // wave-uniform LDS dst base
    char* lB = (char*)&Bs[0][0][0] + w * 1024;
    const size_t rowK64 = (size_t)64 * K;

    // hid: 0 = B-half0, 1 = B-half1, 2 = A-half0, 3 = A-half1
    auto stage = [&](int bufX, int tt, int hid) {
        if (tt >= NT) return;
        const int hf = hid & 1;
        const unsigned short* g = (hid < 2 ? gB : gA) + (size_t)hf * 128 * K + (size_t)tt * 64;
        char* l = (hid < 2 ? lB : lA) + bufX * 32768 + hf * 16384;
        __builtin_amdgcn_global_load_lds((const AS1 void*)g, (AS3 void*)l, 16, 0, 0);
        __builtin_amdgcn_global_load_lds((const AS1 void*)(g + rowK64),
                                         (AS3 void*)(l + 8192), 16, 0, 0);
    };

    f32x4 acc[8][4] = {};

    // prologue: tile0 complete + tile1 {B0,B1,A0} in flight
    stage(0, 0, 0); stage(0, 0, 1); stage(0, 0, 2); stage(0, 0, 3);
    asm volatile("s_waitcnt vmcnt(4)" ::: "memory");
    stage(1, 1, 0); stage(1, 1, 1); stage(1, 1, 2);
    asm volatile("s_waitcnt vmcnt(6)" ::: "memory");
    __builtin_amdgcn_s_barrier();

    const int arow = wr * 128 + lr;
    const int brow = wc * 64 + lr;

    for (int t = 0; t < NT; ++t) {
        const int buf = t & 1;
        const unsigned short* Ab = &As[buf][0][0];
        const unsigned short* Bb = &Bs[buf][0][0];
        bf16x8 bfr[4][2], af[2][2];

#define LDA(Q) \
        af[0][0] = *(const bf16x8*)(Ab + (arow + (2*(Q))*16) * 64 + o0); \
        af[0][1] = *(const bf16x8*)(Ab + (arow + (2*(Q))*16) * 64 + o1); \
        af[1][0] = *(const bf16x8*)(Ab + (arow + (2*(Q)+1)*16) * 64 + o0); \
        af[1][1] = *(const bf16x8*)(Ab + (arow + (2*(Q)+1)*16) * 64 + o1);

#define MMA(Q) \
        __builtin_amdgcn_s_barrier(); \
        __builtin_amdgcn_s_setprio(1); \
        _Pragma("unroll") \
        for (int j = 0; j < 4; ++j) { \
            acc[2*(Q)][j]   = __builtin_amdgcn_mfma_f32_16x16x32_bf16(af[0][0], bfr[j][0], acc[2*(Q)][j], 0, 0, 0); \
            acc[2*(Q)][j]   = __builtin_amdgcn_mfma_f32_16x16x32_bf16(af[0][1], bfr[j][1], acc[2*(Q)][j], 0, 0, 0); \
            acc[2*(Q)+1][j] = __builtin_amdgcn_mfma_f32_16x16x32_bf16(af[1][0], bfr[j][0], acc[2*(Q)+1][j], 0, 0, 0); \
            acc[2*(Q)+1][j] = __builtin_amdgcn_mfma_f32_16x16x32_bf16(af[1][1], bfr[j][1], acc[2*(Q)+1][j], 0, 0, 0); \
        } \
        __builtin_amdgcn_s_setprio(0); \
        __builtin_amdgcn_s_barrier();

        // ---- phase 0: A-quad0 + all B, stage (t+1).A1 -> buf^1
        LDA(0)
#pragma unroll
        for (int j = 0; j < 4; ++j) {
            bfr[j][0] = *(const bf16x8*)(Bb + (brow + j * 16) * 64 + o0);
            bfr[j][1] = *(const bf16x8*)(Bb + (brow + j * 16) * 64 + o1);
        }
        stage(buf ^ 1, t + 1, 3);
        MMA(0)
        // ---- phase 1: A-quad1, stage (t+2).B0 -> buf
        LDA(1)
        stage(buf, t + 2, 0);
        MMA(1)
        // ---- phase 2: A-quad2, stage (t+2).B1 -> buf
        LDA(2)
        stage(buf, t + 2, 1);
        MMA(2)
        // ---- phase 3: A-quad3, stage (t+2).A0 -> buf, counted wait
        LDA(3)
        stage(buf, t + 2, 2);
        if (t + 2 < NT) { asm volatile("s_waitcnt vmcnt(6)" ::: "memory"); }
        else            { asm volatile("s_waitcnt vmcnt(0)" ::: "memory"); }
        MMA(3)
#undef LDA
#undef MMA
    }

    const int crow0 = by * 256 + wr * 128 + quad * 4;
    const int ccol0 = bx * 256 + wc * 64 + lr;
#pragma unroll
    for (int f = 0; f < 8; ++f)
#pragma unroll
        for (int j = 0; j < 4; ++j) {
            const int col = ccol0 + j * 16;
#pragma unroll
            for (int r = 0; r < 4; ++r) {
                size_t idx = (size_t)(crow0 + f * 16 + r) * N + col;
                C[idx] = f2bf(acc[f][j][r] * scale);
            }
        }
}

// ---------------- fused neighbor attention ----------------
__global__ __launch_bounds__(256, 4)
void attn_kernel(const unsigned short* __restrict__ q,
                 const unsigned short* __restrict__ kvb,
                 unsigned short* __restrict__ ao) {
    __shared__ __align__(16) unsigned short qs[4][4][72];
    __shared__ __align__(16) unsigned short ks[4][16][72];
    __shared__ __align__(16) unsigned short vs[4][16][72];
    __shared__ float ps[4][4][17];

    const int t = threadIdx.x, w = t >> 6, lane = t & 63;
    const int bs = blockIdx.x >> 1;
    const int kv = (blockIdx.x & 1) * 4 + w;

    if (lane < 32) {
        int g = lane >> 3, part = lane & 7;
        *(int4*)(&qs[w][g][part * 8]) =
            *(const int4*)(q + (size_t)bs * 2048 + kv * 256 + lane * 8);
    }
#pragma unroll
    for (int p = 0; p < 2; p++) {
        int n = p * 8 + (lane >> 3), part = lane & 7;
        size_t src = ((size_t)bs * 16 + n) * 1024 + kv * 64 + part * 8;
        *(int4*)(&ks[w][n][part * 8]) = *(const int4*)(kvb + src);
        *(int4*)(&vs[w][n][part * 8]) = *(const int4*)(kvb + src + 512);
    }
    __syncthreads();

    {
        const int g = lane & 3, n = lane >> 2;
        const unsigned short* qr = qs[w][g];
        const unsigned short* kr = ks[w][n];
        float s = 0.f;
#pragma unroll
        for (int d = 0; d < 64; d += 2) {
            unsigned uq = *(const unsigned*)(qr + d);
            unsigned uk = *(const unsigned*)(kr + d);
            s += bf_lo(uq) * bf_lo(uk) + bf_hi(uq) * bf_hi(uk);
        }
        float m = s;
#pragma unroll
        for (int off = 4; off < 64; off <<= 1) m = fmaxf(m, __shfl_xor(m, off));
        float e = __expf(s - m);
        float sum = e;
#pragma unroll
        for (int off = 4; off < 64; off <<= 1) sum += __shfl_xor(sum, off);
        ps[w][g][n] = e / sum;
    }
    __syncthreads();

    {
        const int g = lane & 3, d0 = (lane >> 2) * 4;
        float o0 = 0, o1 = 0, o2 = 0, o3 = 0;
#pragma unroll
        for (int n = 0; n < 16; n++) {
            float pv = ps[w][g][n];
            unsigned u0 = *(const unsigned*)(&vs[w][n][d0]);
            unsigned u1 = *(const unsigned*)(&vs[w][n][d0 + 2]);
            o0 += pv * bf_lo(u0); o1 += pv * bf_hi(u0);
            o2 += pv * bf_lo(u1); o3 += pv * bf_hi(u1);
        }
        unsigned r0 = ((unsigned)f2bf(o1) << 16) | f2bf(o0);
        unsigned r1 = ((unsigned)f2bf(o3) << 16) | f2bf(o2);
        uint2 rr = make_uint2(r0, r1);
        *(uint2*)(ao + (size_t)bs * 2048 + kv * 256 + g * 64 + d0) = rr;
    }
}

extern "C" void kernel_launch(void* const* d_in, const int* in_sizes, int n_in,
                              void* d_out, int out_size, void* d_ws, size_t ws_size,
                              hipStream_t stream) {
    (void)in_sizes; (void)n_in; (void)out_size; (void)ws_size;
    const float* hs = (const float*)d_in[0];
    const float* rh = (const float*)d_in[1];
    const float* Wq = (const float*)d_in[2];
    const float* Wk = (const float*)d_in[3];
    const float* Wv = (const float*)d_in[4];
    const float* Wo = (const float*)d_in[5];
    float* out = (float*)d_out;

    const int BS = 4096;            // B*S
    const int H = 2048, RH = 1024, KVD = 512, NN = 16;

    char* ws = (char*)d_ws;
    auto alloc = [&](size_t elems) {
        unsigned short* p = (unsigned short*)ws;
        ws += elems * 2;
        return p;
    };
    unsigned short* hs_b = alloc((size_t)BS * H);
    unsigned short* rh_b = alloc((size_t)BS * NN * RH);
    unsigned short* wq_b = alloc((size_t)H * H);
    unsigned short* wk_b = alloc((size_t)KVD * RH);      // contiguous with wv_b:
    unsigned short* wv_b = alloc((size_t)KVD * RH);      // stacked Wkv [1024,1024]
    unsigned short* wo_b = alloc((size_t)H * H);
    unsigned short* q_b  = alloc((size_t)BS * H);
    unsigned short* kv_b = alloc((size_t)BS * NN * 2 * KVD);
    unsigned short* ao_b = hs_b;   // reuse: hs_b dead after Q-GEMM
    (void)wv_b;

    CastArgs ca;
    ca.s[0] = hs;  ca.d[0] = hs_b;
    ca.s[1] = rh;  ca.d[1] = rh_b;
    ca.s[2] = Wq;  ca.d[2] = wq_b;
    ca.s[3] = Wk;  ca.d[3] = wk_b;
    ca.s[4] = Wv;  ca.d[4] = wv_b;
    ca.s[5] = Wo;  ca.d[5] = wo_b;
    long sizes[6] = {(long)BS * H, (long)BS * NN * RH, (long)H * H,
                     (long)KVD * RH, (long)KVD * RH, (long)H * H};
    long acc = 0;
    for (int i = 0; i < 6; i++) { acc += sizes[i]; ca.end[i] = acc; }
    long total = acc;
    int cast_blocks = (int)((total / 8 + 255) / 256);
    cast_all<<<cast_blocks, 256, 0, stream>>>(ca, total);

    // q = (hs @ Wq^T) * HD^-0.5   (128^2 kernel + XCD swizzle; grid 512 blocks)
    gemm_bt<0><<<dim3(H / 128, BS / 128), 256, 0, stream>>>(
        hs_b, wq_b, q_b, BS, H, H, 0.125f);
    // kv = retrieved @ [Wk;Wv]^T  -- 256^2 8-phase kernel; grid (4,256)=1024 blocks
    gemm256_bt<<<dim3((2 * KVD) / 256, (BS * NN) / 256), 512, 0, stream>>>(
        rh_b, wk_b, kv_b, BS * NN, 2 * KVD, RH, 1.0f);
    // fused per-position attention
    attn_kernel<<<BS * 2, 256, 0, stream>>>(q_b, kv_b, ao_b);
    // final projection -> fp32 output
    gemm_bt<1><<<dim3(H / 128, BS / 128), 256, 0, stream>>>(
        ao_b, wo_b, out, BS, H, H, 1.0f);
}